// Round 3
// baseline (918.354 us; speedup 1.0000x reference)
//
#include <hip/hip_runtime.h>
#include <hip/hip_bf16.h>
#include <cstdint>

#define WS_    7
#define SHIFT_ 3
#define NH_    8
#define HD_    32
#define C_     256
#define H_     112
#define W_     112
#define B_     8
#define WSQ    49
#define ROWS   100352   // B*H*W == B*nW*49
#define HIDDEN 1024

typedef __attribute__((ext_vector_type(8))) short short8;
typedef __attribute__((ext_vector_type(4))) float f32x4;

__device__ inline ushort f2bf(float f){
  uint32_t u = __float_as_uint(f);
  u += 0x7fffu + ((u >> 16) & 1u);
  return (ushort)(u >> 16);
}

__device__ inline int row2tok(int r){
  int w  = r / WSQ, p = r - w * WSQ;
  int b  = w >> 8, wi = w & 255;
  int wh = wi >> 4, ww = wi & 15;
  int i  = p / WS_, j = p - i * WS_;
  int h  = wh * WS_ + i + SHIFT_; if (h >= H_) h -= H_;
  int wc = ww * WS_ + j + SHIFT_; if (wc >= W_) wc -= W_;
  return b * (H_ * W_) + h * W_ + wc;
}

// ---------------- weight transpose + cast ----------------
__global__ void transpose_cast(const float* __restrict__ in, ushort* __restrict__ out,
                               int K, int N){
  int idx = blockIdx.x * 256 + threadIdx.x;
  if (idx >= K * N) return;
  int k = idx / N, n = idx - k * N;
  out[(size_t)n * K + k] = f2bf(in[idx]);
}

// ---------------- LayerNorm (optionally fused with window gather) ----------------
template<bool GATHER>
__global__ __launch_bounds__(256) void ln_kernel(const float* __restrict__ x,
    const float* __restrict__ g, const float* __restrict__ b, ushort* __restrict__ out)
{
  int wave = threadIdx.x >> 6, lane = threadIdx.x & 63;
  int r = blockIdx.x * 4 + wave;
  int t = GATHER ? row2tok(r) : r;
  const float4 v = *(const float4*)(x + (size_t)t * C_ + lane * 4);
  float s  = v.x + v.y + v.z + v.w;
  float s2 = v.x * v.x + v.y * v.y + v.z * v.z + v.w * v.w;
  #pragma unroll
  for (int m = 32; m; m >>= 1){ s += __shfl_xor(s, m); s2 += __shfl_xor(s2, m); }
  float mean = s * (1.f / C_);
  float inv  = rsqrtf(fmaxf(s2 * (1.f / C_) - mean * mean, 0.f) + 1e-5f);
  int c0 = lane * 4;
  ushort4 o;
  o.x = f2bf((v.x - mean) * inv * g[c0 + 0] + b[c0 + 0]);
  o.y = f2bf((v.y - mean) * inv * g[c0 + 1] + b[c0 + 1]);
  o.z = f2bf((v.z - mean) * inv * g[c0 + 2] + b[c0 + 2]);
  o.w = f2bf((v.w - mean) * inv * g[c0 + 3] + b[c0 + 3]);
  *(ushort4*)(out + (size_t)r * C_ + c0) = o;
}

// ---------------- 256x256 8-phase bf16 GEMM (T1+T2+T3+T4+T5) ----------------
__device__ inline void gll16(const void* g, void* l){
  __builtin_amdgcn_global_load_lds(
      (__attribute__((address_space(1))) void*)g,
      (__attribute__((address_space(3))) void*)l, 16, 0, 0);
}

// EPI: 0 = +bias -> bf16 (qkv)
//      1 = +bias + window-reverse scatter + residual(x, token order) -> f32
//      2 = +bias + exact GELU -> bf16
//      3 = +bias + residual(row order) -> f32
template<int EPI>
__global__ __launch_bounds__(512, 2) void gemm8p(
    const ushort* __restrict__ A,   // M x K row-major bf16
    const ushort* __restrict__ Bt,  // N x K row-major bf16
    const float*  __restrict__ bias,
    void*         __restrict__ Cout,
    const float*  __restrict__ resid,
    int M, int N, int K, int nN)
{
  __shared__ __align__(16) ushort sA[2][256 * 64];
  __shared__ __align__(16) ushort sB[2][256 * 64];
  const int tid  = threadIdx.x;
  const int wave = tid >> 6, lane = tid & 63;
  const int wr   = wave >> 2, wc = wave & 3;     // 2M x 4N waves; 128x64 each
  const int la   = lane & 15, lg = lane >> 4;
  const int l8   = lane >> 3, l7 = lane & 7;

  // bijective XCD swizzle (all grids here divisible by 8)
  const int cpx  = gridDim.x >> 3;
  const int lid  = (blockIdx.x & 7) * cpx + (blockIdx.x >> 3);
  const int rowb = lid / nN, colb = lid - rowb * nN;
  const int m0   = rowb * 256, n0 = colb * 256;

  // --- staging addressing (inverse-swizzled global source, linear LDS dest) ---
  const int swe      = (l7 ^ l8) * 8;                    // source col-elem offset
  const int arow_off = (wave < 4 ? wave * 8 : 128 + (wave - 4) * 8) + l8;  // + q*32
  const int brow_off = wave * 8 + l8;                                      // + c*64
  const ushort* gA = A  + (size_t)(m0 + arow_off) * K + swe;
  const ushort* gB = Bt + (size_t)(n0 + brow_off) * K + swe;

#define STAGE_A(b, q, k0) gll16(gA + (size_t)(q) * 32 * K + (k0), &sA[b][(arow_off + (q) * 32) * 64 + l7 * 8])
#define STAGE_B(b, c, k0) gll16(gB + (size_t)(c) * 64 * K + (k0), &sB[b][(brow_off + (c) * 64) * 64 + l7 * 8])

  // --- read addressing (swizzled ds_read) ---
  const int arow_rd = wr * 128 + la;
  const int brow_rd = wc * 64 + la;
  const int col0    = lg * 8;
  const int xorm    = l7 * 8;
#define LDA(sAb, m, ks) (*(const short8*)&(sAb)[(arow_rd + (m) * 16) * 64 + ((((ks) * 32) + col0) ^ xorm)])
#define LDB(sBb, n, ks) (*(const short8*)&(sBb)[(brow_rd + (n) * 16) * 64 + ((((ks) * 32) + col0) ^ xorm)])

  f32x4 acc[8][4] = {};
  const int nt = K >> 6;   // BK=64; nt >= 4 for all our shapes

  // prologue: tile0 fully, tile1 first 6 chunks
  STAGE_A(0, 0, 0); STAGE_B(0, 0, 0);
  STAGE_A(0, 1, 0); STAGE_B(0, 1, 0);
  STAGE_A(0, 2, 0); STAGE_B(0, 2, 0);
  STAGE_A(0, 3, 0); STAGE_B(0, 3, 0);
  STAGE_A(1, 0, 64); STAGE_B(1, 0, 64);
  STAGE_A(1, 1, 64); STAGE_B(1, 1, 64);
  STAGE_A(1, 2, 64); STAGE_B(1, 2, 64);

#define TILE(TT, S1c, S2c, VMLIT) do {                                        \
    const int b_ = (TT) & 1; const int kc_ = (TT) * 64;                        \
    ushort* sAb = sA[b_]; ushort* sBb = sB[b_];                                \
    const bool S1_ = (S1c), S2_ = (S2c);                                       \
    /* phase 0: stage last chunk of tile TT+1, checkpoint, B-all + A-band0 */  \
    if (S1_){ STAGE_A(b_ ^ 1, 3, kc_ + 64); STAGE_B(b_ ^ 1, 3, kc_ + 64); }    \
    asm volatile("s_waitcnt vmcnt(" VMLIT ")" ::: "memory");                   \
    __builtin_amdgcn_s_barrier();                                              \
    short8 bfr[4][2], af[2][2];                                                \
    _Pragma("unroll") for (int n = 0; n < 4; n++)                              \
      { _Pragma("unroll") for (int ks = 0; ks < 2; ks++) bfr[n][ks] = LDB(sBb, n, ks); } \
    _Pragma("unroll") for (int mi = 0; mi < 2; mi++)                           \
      { _Pragma("unroll") for (int ks = 0; ks < 2; ks++) af[mi][ks] = LDA(sAb, mi, ks); } \
    __builtin_amdgcn_s_setprio(1);                                             \
    _Pragma("unroll") for (int mi = 0; mi < 2; mi++)                           \
      { _Pragma("unroll") for (int n = 0; n < 4; n++)                          \
        { _Pragma("unroll") for (int ks = 0; ks < 2; ks++)                     \
          acc[mi][n] = __builtin_amdgcn_mfma_f32_16x16x32_bf16(af[mi][ks], bfr[n][ks], acc[mi][n], 0, 0, 0); } } \
    __builtin_amdgcn_s_setprio(0);                                             \
    __builtin_amdgcn_s_barrier();                                              \
    /* phases 1..3: stage chunks (q-1) of tile TT+2 into freed bands of buf b_ */ \
    _Pragma("unroll") for (int q = 1; q < 4; q++){                             \
      if (S2_){ STAGE_A(b_, q - 1, kc_ + 128); STAGE_B(b_, q - 1, kc_ + 128); } \
      _Pragma("unroll") for (int mi = 0; mi < 2; mi++)                         \
        { _Pragma("unroll") for (int ks = 0; ks < 2; ks++) af[mi][ks] = LDA(sAb, q * 2 + mi, ks); } \
      __builtin_amdgcn_s_setprio(1);                                           \
      _Pragma("unroll") for (int mi = 0; mi < 2; mi++)                         \
        { _Pragma("unroll") for (int n = 0; n < 4; n++)                        \
          { _Pragma("unroll") for (int ks = 0; ks < 2; ks++)                   \
            acc[q * 2 + mi][n] = __builtin_amdgcn_mfma_f32_16x16x32_bf16(af[mi][ks], bfr[n][ks], acc[q * 2 + mi][n], 0, 0, 0); } } \
      __builtin_amdgcn_s_setprio(0);                                           \
      __builtin_amdgcn_s_barrier();                                            \
    }                                                                          \
  } while (0)

  for (int t = 0; t < nt - 1; ++t) TILE(t, true, (t + 2) < nt, "8");
  TILE(nt - 1, false, false, "0");

#undef TILE
#undef LDA
#undef LDB
#undef STAGE_A
#undef STAGE_B

  // ---------------- epilogue ----------------
  #pragma unroll
  for (int m = 0; m < 8; m++){
    #pragma unroll
    for (int n = 0; n < 4; n++){
      int col = n0 + wc * 64 + n * 16 + la;
      float bs = bias[col];
      #pragma unroll
      for (int q = 0; q < 4; q++){
        int row = m0 + wr * 128 + m * 16 + lg * 4 + q;
        float v = acc[m][n][q] + bs;
        if (EPI == 0){
          ((ushort*)Cout)[(size_t)row * N + col] = f2bf(v);
        } else if (EPI == 1){
          int t = row2tok(row);
          size_t o = (size_t)t * C_ + col;
          ((float*)Cout)[o] = resid[o] + v;
        } else if (EPI == 2){
          float gx = 0.5f * v * (1.f + erff(v * 0.70710678118f));
          ((ushort*)Cout)[(size_t)row * N + col] = f2bf(gx);
        } else {
          size_t o = (size_t)row * C_ + col;
          ((float*)Cout)[o] = resid[o] + v;
        }
      }
    }
  }
}

// ---------------- windowed attention: one wave per (window, head) ----------------
__global__ __launch_bounds__(256, 2) void attn_kernel(const ushort* __restrict__ qkv,
    const float* __restrict__ mask, ushort* __restrict__ out)
{
  __shared__ __align__(16) ushort P [4][64 * 72];
  __shared__ __align__(16) ushort VT[4][32 * 72];
  const int wave = threadIdx.x >> 6, lane = threadIdx.x & 63;
  const int gid  = blockIdx.x * 4 + wave;
  const int w    = gid >> 3, head = gid & 7;
  const int la   = lane & 15, lg = lane >> 4;
  const ushort* qb = qkv + (size_t)w * WSQ * 768 + head * HD_;
  const short8 z8 = {0,0,0,0,0,0,0,0};

  {
    ushort4 z4 = {0,0,0,0};
    for (int idx = lane; idx < (32 * 72) / 4; idx += 64) ((ushort4*)VT[wave])[idx] = z4;
    for (int idx = lane; idx < WSQ * 4; idx += 64){
      int row = idx >> 2, db = idx & 3;
      short8 vv = *(const short8*)&qb[(size_t)row * 768 + 512 + db * 8];
      #pragma unroll
      for (int e = 0; e < 8; e++) VT[wave][(db * 8 + e) * 72 + row] = ((ushort*)&vv)[e];
    }
  }

  short8 qf[4], kf[4];
  #pragma unroll
  for (int i = 0; i < 4; i++){
    int m = i * 16 + la;
    qf[i] = (m < WSQ) ? *(const short8*)&qb[(size_t)m * 768 +       lg * 8] : z8;
    kf[i] = (m < WSQ) ? *(const short8*)&qb[(size_t)m * 768 + 256 + lg * 8] : z8;
  }

  f32x4 s[4][4] = {};
  #pragma unroll
  for (int i = 0; i < 4; i++)
    #pragma unroll
    for (int j = 0; j < 4; j++)
      s[i][j] = __builtin_amdgcn_mfma_f32_16x16x32_bf16(qf[i], kf[j], s[i][j], 0, 0, 0);

  const float* mrow = mask + (size_t)(w & 255) * WSQ * WSQ;
  const float scale = 0.17677669529663687f;
  float rinv[4][4];
  #pragma unroll
  for (int i = 0; i < 4; i++){
    #pragma unroll
    for (int q = 0; q < 4; q++){
      int m = i * 16 + lg * 4 + q;
      float pv[4]; float mx = -1e30f;
      #pragma unroll
      for (int j = 0; j < 4; j++){
        int n = j * 16 + la;
        float val = (m < WSQ && n < WSQ) ? s[i][j][q] * scale + mrow[m * WSQ + n] : -1e30f;
        pv[j] = val; mx = fmaxf(mx, val);
      }
      #pragma unroll
      for (int msk = 1; msk < 16; msk <<= 1) mx = fmaxf(mx, __shfl_xor(mx, msk));
      float sum = 0.f;
      #pragma unroll
      for (int j = 0; j < 4; j++){ float e = __expf(pv[j] - mx); pv[j] = e; sum += e; }
      #pragma unroll
      for (int msk = 1; msk < 16; msk <<= 1) sum += __shfl_xor(sum, msk);
      rinv[i][q] = 1.f / sum;
      #pragma unroll
      for (int j = 0; j < 4; j++) P[wave][m * 72 + j * 16 + la] = f2bf(pv[j]);
    }
  }

  f32x4 o[4][2] = {};
  #pragma unroll
  for (int kk = 0; kk < 2; kk++){
    short8 pf[4], vf[2];
    #pragma unroll
    for (int i = 0; i < 4; i++)  pf[i]  = *(const short8*)&P [wave][(i  * 16 + la) * 72 + kk * 32 + lg * 8];
    #pragma unroll
    for (int jn = 0; jn < 2; jn++) vf[jn] = *(const short8*)&VT[wave][(jn * 16 + la) * 72 + kk * 32 + lg * 8];
    #pragma unroll
    for (int i = 0; i < 4; i++)
      #pragma unroll
      for (int jn = 0; jn < 2; jn++)
        o[i][jn] = __builtin_amdgcn_mfma_f32_16x16x32_bf16(pf[i], vf[jn], o[i][jn], 0, 0, 0);
  }

  ushort* ob = out + (size_t)w * WSQ * C_ + head * HD_;
  #pragma unroll
  for (int i = 0; i < 4; i++)
    #pragma unroll
    for (int jn = 0; jn < 2; jn++)
      #pragma unroll
      for (int q = 0; q < 4; q++){
        int m = i * 16 + lg * 4 + q;
        if (m < WSQ) ob[(size_t)m * C_ + jn * 16 + la] = f2bf(o[i][jn][q] * rinv[i][q]);
      }
}

// ---------------- launch ----------------
extern "C" void kernel_launch(void* const* d_in, const int* in_sizes, int n_in,
                              void* d_out, int out_size, void* d_ws, size_t ws_size,
                              hipStream_t stream)
{
  const float* x      = (const float*)d_in[0];
  const float* mask   = (const float*)d_in[1];
  const float* n1g    = (const float*)d_in[2];
  const float* n1b    = (const float*)d_in[3];
  const float* qkv_w  = (const float*)d_in[4];
  const float* qkv_b  = (const float*)d_in[5];
  const float* proj_w = (const float*)d_in[6];
  const float* proj_b = (const float*)d_in[7];
  const float* n2g    = (const float*)d_in[8];
  const float* n2b    = (const float*)d_in[9];
  const float* fc1_w  = (const float*)d_in[10];
  const float* fc1_b  = (const float*)d_in[11];
  const float* fc2_w  = (const float*)d_in[12];
  const float* fc2_b  = (const float*)d_in[13];

  char* ws = (char*)d_ws;
  ushort* R1 = (ushort*)ws;
  ushort* R2 = (ushort*)(ws + 51380224);
  float*  x2 = (float*) (ws + 51380224 + 205520896);
  ushort* wqT = (ushort*)(ws + 51380224 + 205520896 + 102760448);
  ushort* wpT = wqT + 768 * 256;
  ushort* w1T = wpT + 256 * 256;
  ushort* w2T = w1T + 1024 * 256;

  transpose_cast<<<(256 * 768  + 255) / 256, 256, 0, stream>>>(qkv_w,  wqT, 256, 768);
  transpose_cast<<<(256 * 256  + 255) / 256, 256, 0, stream>>>(proj_w, wpT, 256, 256);
  transpose_cast<<<(256 * 1024 + 255) / 256, 256, 0, stream>>>(fc1_w,  w1T, 256, 1024);
  transpose_cast<<<(1024 * 256 + 255) / 256, 256, 0, stream>>>(fc2_w,  w2T, 1024, 256);

  ln_kernel<true><<<ROWS / 4, 256, 0, stream>>>(x, n1g, n1b, R1);
  gemm8p<0><<<392 * 3, 512, 0, stream>>>(R1, wqT, qkv_b, R2, nullptr, ROWS, 768, 256, 3);
  attn_kernel<<<(2048 * 8) / 4, 256, 0, stream>>>(R2, mask, R1);
  gemm8p<1><<<392 * 1, 512, 0, stream>>>(R1, wpT, proj_b, x2, x, ROWS, 256, 256, 1);
  ln_kernel<false><<<ROWS / 4, 256, 0, stream>>>(x2, n2g, n2b, R1);
  gemm8p<2><<<392 * 4, 512, 0, stream>>>(R1, w1T, fc1_b, R2, nullptr, ROWS, 1024, 256, 4);
  gemm8p<3><<<392 * 1, 512, 0, stream>>>(R2, w2T, fc2_b, d_out, x2, ROWS, 256, 1024, 1);
}

// Round 5
// 682.066 us; speedup vs baseline: 1.3464x; 1.3464x over previous
//
#include <hip/hip_runtime.h>
#include <hip/hip_bf16.h>
#include <cstdint>

#define WS_    7
#define SHIFT_ 3
#define NH_    8
#define HD_    32
#define C_     256
#define H_     112
#define W_     112
#define B_     8
#define WSQ    49
#define ROWS   100352   // B*H*W == B*nW*49
#define HIDDEN 1024

typedef __attribute__((ext_vector_type(8))) short short8;
typedef __attribute__((ext_vector_type(4))) float f32x4;

__device__ inline ushort f2bf(float f){
  uint32_t u = __float_as_uint(f);
  u += 0x7fffu + ((u >> 16) & 1u);
  return (ushort)(u >> 16);
}
__device__ inline float bf2f(ushort s){ return __uint_as_float(((uint32_t)s) << 16); }

__device__ inline int row2tok(int r){
  int w  = r / WSQ, p = r - w * WSQ;
  int b  = w >> 8, wi = w & 255;
  int wh = wi >> 4, ww = wi & 15;
  int i  = p / WS_, j = p - i * WS_;
  int h  = wh * WS_ + i + SHIFT_; if (h >= H_) h -= H_;
  int wc = ww * WS_ + j + SHIFT_; if (wc >= W_) wc -= W_;
  return b * (H_ * W_) + h * W_ + wc;
}

// ---------------- weight transpose + cast ----------------
__global__ void transpose_cast(const float* __restrict__ in, ushort* __restrict__ out,
                               int K, int N){
  int idx = blockIdx.x * 256 + threadIdx.x;
  if (idx >= K * N) return;
  int k = idx / N, n = idx - k * N;
  out[(size_t)n * K + k] = f2bf(in[idx]);
}

// ---------------- LayerNorm fused with window gather (LN1) ----------------
__global__ __launch_bounds__(256) void ln_kernel(const float* __restrict__ x,
    const float* __restrict__ g, const float* __restrict__ b, ushort* __restrict__ out)
{
  int wave = threadIdx.x >> 6, lane = threadIdx.x & 63;
  int r = blockIdx.x * 4 + wave;
  int t = row2tok(r);
  const float4 v = *(const float4*)(x + (size_t)t * C_ + lane * 4);
  float s  = v.x + v.y + v.z + v.w;
  float s2 = v.x * v.x + v.y * v.y + v.z * v.z + v.w * v.w;
  #pragma unroll
  for (int m = 32; m; m >>= 1){ s += __shfl_xor(s, m); s2 += __shfl_xor(s2, m); }
  float mean = s * (1.f / C_);
  float inv  = rsqrtf(fmaxf(s2 * (1.f / C_) - mean * mean, 0.f) + 1e-5f);
  int c0 = lane * 4;
  ushort4 o;
  o.x = f2bf((v.x - mean) * inv * g[c0 + 0] + b[c0 + 0]);
  o.y = f2bf((v.y - mean) * inv * g[c0 + 1] + b[c0 + 1]);
  o.z = f2bf((v.z - mean) * inv * g[c0 + 2] + b[c0 + 2]);
  o.w = f2bf((v.w - mean) * inv * g[c0 + 3] + b[c0 + 3]);
  *(ushort4*)(out + (size_t)r * C_ + c0) = o;
}

// ---------------- 128x256 bf16 GEMM, 3-buf depth-2 pipeline, counted vmcnt ----------------
__device__ inline void gll16(const void* g, void* l){
  __builtin_amdgcn_global_load_lds(
      (__attribute__((address_space(1))) void*)g,
      (__attribute__((address_space(3))) void*)l, 16, 0, 0);
}

// EPI: 0 = +bias -> bf16 (qkv)
//      1 = +bias + residual(x via row2tok) -> f32 x2[r] (linear), + fused LN2 -> bf16 outLN[r]
//          (nN==1: block owns rows [m0,m0+128) exclusively; outLN may alias A)
//      2 = +bias + exact GELU -> bf16
//      3 = +bias + residual(linear) -> f32, scattered to token order via row2tok
template<int EPI>
__global__ __launch_bounds__(512, 4) void gemmW(
    const ushort* __restrict__ A,   // M x K row-major bf16 (window-row order)
    const ushort* __restrict__ Bt,  // N x K row-major bf16 (transposed weight)
    const float*  __restrict__ bias,
    void*         __restrict__ Cout,
    const float*  __restrict__ resid,
    const float*  __restrict__ g2,   // EPI==1 only
    const float*  __restrict__ b2,   // EPI==1 only
    ushort*       __restrict__ outLN,// EPI==1 only
    int M, int N, int K, int nN)
{
  union SMem {
    struct { ushort lA[3][128 * 32]; ushort lB[3][256 * 32]; } g;   // 72 KB
    struct { ushort stile[128][256]; float red[128][4][2]; } e;     // 68 KB (EPI==1 epilogue)
  };
  __shared__ __align__(16) SMem sm;

  const int tid  = threadIdx.x;
  const int cpx  = gridDim.x >> 3;
  const int lid  = (blockIdx.x & 7) * cpx + (blockIdx.x >> 3);
  const int rowb = lid / nN, colb = lid - rowb * nN;
  const int m0   = rowb * 128, n0 = colb * 256;

  const int wave = tid >> 6, lane = tid & 63;
  const int wr   = wave >> 2, wc = wave & 3;    // 2 x 4 wave grid, 64x64 each
  const int la   = lane & 15, lg = lane >> 4;

  f32x4 acc[4][4] = {};

  const int r0 = tid >> 2, kp = (tid & 3) * 8;
  const ushort* gA  = A  + (size_t)(m0 + r0)       * K + kp;
  const ushort* gB0 = Bt + (size_t)(n0 + r0)       * K + kp;
  const ushort* gB1 = Bt + (size_t)(n0 + r0 + 128) * K + kp;

  const int nt = K >> 5;

  // prologue: stage tiles 0 and 1 (FIFO per wave: tile0's 3 loads oldest)
  gll16(gA,       &sm.g.lA[0][tid * 8]);
  gll16(gB0,      &sm.g.lB[0][tid * 8]);
  gll16(gB1,      &sm.g.lB[0][(tid + 512) * 8]);
  gll16(gA  + 32, &sm.g.lA[1][tid * 8]);
  gll16(gB0 + 32, &sm.g.lB[1][tid * 8]);
  gll16(gB1 + 32, &sm.g.lB[1][(tid + 512) * 8]);

  for (int t = 0; t < nt; ++t){
    // wait own tile-t loads (oldest 3); barrier joins all waves -> tile t fully staged
    if (t + 1 < nt) asm volatile("s_waitcnt vmcnt(3)" ::: "memory");
    else            asm volatile("s_waitcnt vmcnt(0)" ::: "memory");
    __builtin_amdgcn_s_barrier();

    // stage tile t+2 into the buffer freed at iter t-1 (all waves past barrier => consumed)
    const int tn = t + 2;
    if (tn < nt){
      const int bn = tn % 3, k0 = tn * 32;
      gll16(gA  + k0, &sm.g.lA[bn][tid * 8]);
      gll16(gB0 + k0, &sm.g.lB[bn][tid * 8]);
      gll16(gB1 + k0, &sm.g.lB[bn][(tid + 512) * 8]);
    }

    const int bc = t % 3;
    const ushort* pA = sm.g.lA[bc];
    const ushort* pB = sm.g.lB[bc];
    short8 af[4], bfr[4];
    #pragma unroll
    for (int i = 0; i < 4; i++) af[i]  = *(const short8*)&pA[(wr * 64 + i * 16 + la) * 32 + lg * 8];
    #pragma unroll
    for (int j = 0; j < 4; j++) bfr[j] = *(const short8*)&pB[(wc * 64 + j * 16 + la) * 32 + lg * 8];
    #pragma unroll
    for (int i = 0; i < 4; i++)
      #pragma unroll
      for (int j = 0; j < 4; j++)
        acc[i][j] = __builtin_amdgcn_mfma_f32_16x16x32_bf16(af[i], bfr[j], acc[i][j], 0, 0, 0);
  }

  // ---------------- epilogue ----------------
  if (EPI != 1){
    #pragma unroll
    for (int i = 0; i < 4; i++){
      #pragma unroll
      for (int j = 0; j < 4; j++){
        int col = n0 + wc * 64 + j * 16 + la;
        float bs = bias[col];
        #pragma unroll
        for (int q = 0; q < 4; q++){
          int row = m0 + wr * 64 + i * 16 + lg * 4 + q;
          float v = acc[i][j][q] + bs;
          if (EPI == 0){
            ((ushort*)Cout)[(size_t)row * N + col] = f2bf(v);
          } else if (EPI == 2){
            float gx = 0.5f * v * (1.f + erff(v * 0.70710678118f));
            ((ushort*)Cout)[(size_t)row * N + col] = f2bf(gx);
          } else {
            // EPI==3: resid linear (window order), output scattered to token order
            int tk = row2tok(row);
            ((float*)Cout)[(size_t)tk * C_ + col] = resid[(size_t)row * C_ + col] + v;
          }
        }
      }
    }
  } else {
    // proj epilogue: s = x[tok(r)] + out[r]; x2[r] = s (f32 linear);
    // fused LN2 over the block's 128 rows (all 256 cols local); outLN[r] bf16 linear.
    __syncthreads();   // all waves done with main-loop LDS reads; safe to reuse LDS
    #pragma unroll
    for (int i = 0; i < 4; i++){
      #pragma unroll
      for (int q = 0; q < 4; q++){
        int rowL = wr * 64 + i * 16 + lg * 4 + q;
        int tk   = row2tok(m0 + rowL);
        float rs = 0.f, rs2 = 0.f;
        #pragma unroll
        for (int n = 0; n < 4; n++){
          int colL = wc * 64 + n * 16 + la;
          float v = acc[i][n][q] + bias[colL];
          float s = resid[(size_t)tk * C_ + colL] + v;
          ((float*)Cout)[(size_t)(m0 + rowL) * C_ + colL] = s;   // x2, window order
          sm.e.stile[rowL][colL] = f2bf(s);
          rs += s; rs2 += s * s;
        }
        #pragma unroll
        for (int msk = 1; msk < 16; msk <<= 1){
          rs  += __shfl_xor(rs,  msk);
          rs2 += __shfl_xor(rs2, msk);
        }
        if (la == 0){ sm.e.red[rowL][wc][0] = rs; sm.e.red[rowL][wc][1] = rs2; }
      }
    }
    __syncthreads();
    #pragma unroll
    for (int i = 0; i < 4; i++){
      #pragma unroll
      for (int q = 0; q < 4; q++){
        int rowL = wr * 64 + i * 16 + lg * 4 + q;
        float s0 = sm.e.red[rowL][0][0] + sm.e.red[rowL][1][0] + sm.e.red[rowL][2][0] + sm.e.red[rowL][3][0];
        float s1 = sm.e.red[rowL][0][1] + sm.e.red[rowL][1][1] + sm.e.red[rowL][2][1] + sm.e.red[rowL][3][1];
        float mean = s0 * (1.f / C_);
        float inv  = rsqrtf(fmaxf(s1 * (1.f / C_) - mean * mean, 0.f) + 1e-5f);
        #pragma unroll
        for (int n = 0; n < 4; n++){
          int colL = wc * 64 + n * 16 + la;
          float s = bf2f(sm.e.stile[rowL][colL]);
          outLN[(size_t)(m0 + rowL) * C_ + colL] = f2bf((s - mean) * inv * g2[colL] + b2[colL]);
        }
      }
    }
  }
}

// ---------------- windowed attention: one wave per (window, head) ----------------
__global__ __launch_bounds__(256, 2) void attn_kernel(const ushort* __restrict__ qkv,
    const float* __restrict__ mask, ushort* __restrict__ out)
{
  __shared__ __align__(16) ushort P [4][64 * 72];
  __shared__ __align__(16) ushort VT[4][32 * 72];
  const int wave = threadIdx.x >> 6, lane = threadIdx.x & 63;
  const int gid  = blockIdx.x * 4 + wave;
  const int w    = gid >> 3, head = gid & 7;
  const int la   = lane & 15, lg = lane >> 4;
  const ushort* qb = qkv + (size_t)w * WSQ * 768 + head * HD_;
  const short8 z8 = {0,0,0,0,0,0,0,0};

  {
    ushort4 z4 = {0,0,0,0};
    for (int idx = lane; idx < (32 * 72) / 4; idx += 64) ((ushort4*)VT[wave])[idx] = z4;
    for (int idx = lane; idx < WSQ * 4; idx += 64){
      int row = idx >> 2, db = idx & 3;
      short8 vv = *(const short8*)&qb[(size_t)row * 768 + 512 + db * 8];
      #pragma unroll
      for (int e = 0; e < 8; e++) VT[wave][(db * 8 + e) * 72 + row] = ((ushort*)&vv)[e];
    }
  }

  short8 qf[4], kf[4];
  #pragma unroll
  for (int i = 0; i < 4; i++){
    int m = i * 16 + la;
    qf[i] = (m < WSQ) ? *(const short8*)&qb[(size_t)m * 768 +       lg * 8] : z8;
    kf[i] = (m < WSQ) ? *(const short8*)&qb[(size_t)m * 768 + 256 + lg * 8] : z8;
  }

  f32x4 s[4][4] = {};
  #pragma unroll
  for (int i = 0; i < 4; i++)
    #pragma unroll
    for (int j = 0; j < 4; j++)
      s[i][j] = __builtin_amdgcn_mfma_f32_16x16x32_bf16(qf[i], kf[j], s[i][j], 0, 0, 0);

  const float* mrow = mask + (size_t)(w & 255) * WSQ * WSQ;
  const float scale = 0.17677669529663687f;
  float rinv[4][4];
  #pragma unroll
  for (int i = 0; i < 4; i++){
    #pragma unroll
    for (int q = 0; q < 4; q++){
      int m = i * 16 + lg * 4 + q;
      float pv[4]; float mx = -1e30f;
      #pragma unroll
      for (int j = 0; j < 4; j++){
        int n = j * 16 + la;
        float val = (m < WSQ && n < WSQ) ? s[i][j][q] * scale + mrow[m * WSQ + n] : -1e30f;
        pv[j] = val; mx = fmaxf(mx, val);
      }
      #pragma unroll
      for (int msk = 1; msk < 16; msk <<= 1) mx = fmaxf(mx, __shfl_xor(mx, msk));
      float sum = 0.f;
      #pragma unroll
      for (int j = 0; j < 4; j++){ float e = __expf(pv[j] - mx); pv[j] = e; sum += e; }
      #pragma unroll
      for (int msk = 1; msk < 16; msk <<= 1) sum += __shfl_xor(sum, msk);
      rinv[i][q] = 1.f / sum;
      #pragma unroll
      for (int j = 0; j < 4; j++) P[wave][m * 72 + j * 16 + la] = f2bf(pv[j]);
    }
  }

  f32x4 o[4][2] = {};
  #pragma unroll
  for (int kk = 0; kk < 2; kk++){
    short8 pf[4], vf[2];
    #pragma unroll
    for (int i = 0; i < 4; i++)  pf[i]  = *(const short8*)&P [wave][(i  * 16 + la) * 72 + kk * 32 + lg * 8];
    #pragma unroll
    for (int jn = 0; jn < 2; jn++) vf[jn] = *(const short8*)&VT[wave][(jn * 16 + la) * 72 + kk * 32 + lg * 8];
    #pragma unroll
    for (int i = 0; i < 4; i++)
      #pragma unroll
      for (int jn = 0; jn < 2; jn++)
        o[i][jn] = __builtin_amdgcn_mfma_f32_16x16x32_bf16(pf[i], vf[jn], o[i][jn], 0, 0, 0);
  }

  ushort* ob = out + (size_t)w * WSQ * C_ + head * HD_;
  #pragma unroll
  for (int i = 0; i < 4; i++)
    #pragma unroll
    for (int jn = 0; jn < 2; jn++)
      #pragma unroll
      for (int q = 0; q < 4; q++){
        int m = i * 16 + lg * 4 + q;
        if (m < WSQ) ob[(size_t)m * C_ + jn * 16 + la] = f2bf(o[i][jn][q] * rinv[i][q]);
      }
}

// ---------------- launch ----------------
extern "C" void kernel_launch(void* const* d_in, const int* in_sizes, int n_in,
                              void* d_out, int out_size, void* d_ws, size_t ws_size,
                              hipStream_t stream)
{
  const float* x      = (const float*)d_in[0];
  const float* mask   = (const float*)d_in[1];
  const float* n1g    = (const float*)d_in[2];
  const float* n1b    = (const float*)d_in[3];
  const float* qkv_w  = (const float*)d_in[4];
  const float* qkv_b  = (const float*)d_in[5];
  const float* proj_w = (const float*)d_in[6];
  const float* proj_b = (const float*)d_in[7];
  const float* n2g    = (const float*)d_in[8];
  const float* n2b    = (const float*)d_in[9];
  const float* fc1_w  = (const float*)d_in[10];
  const float* fc1_b  = (const float*)d_in[11];
  const float* fc2_w  = (const float*)d_in[12];
  const float* fc2_b  = (const float*)d_in[13];

  char* ws = (char*)d_ws;
  ushort* R1 = (ushort*)ws;                                       // attn out -> LN2 out (window order)
  ushort* R2 = (ushort*)(ws + 51380224);                          // qkv -> gelu out (window order)
  float*  x2 = (float*) (ws + 51380224 + 205520896);              // post-attn residual (window order)
  ushort* wqT = (ushort*)(ws + 51380224 + 205520896 + 102760448);
  ushort* wpT = wqT + 768 * 256;
  ushort* w1T = wpT + 256 * 256;
  ushort* w2T = w1T + 1024 * 256;

  transpose_cast<<<(256 * 768  + 255) / 256, 256, 0, stream>>>(qkv_w,  wqT, 256, 768);
  transpose_cast<<<(256 * 256  + 255) / 256, 256, 0, stream>>>(proj_w, wpT, 256, 256);
  transpose_cast<<<(256 * 1024 + 255) / 256, 256, 0, stream>>>(fc1_w,  w1T, 256, 1024);
  transpose_cast<<<(1024 * 256 + 255) / 256, 256, 0, stream>>>(fc2_w,  w2T, 1024, 256);

  ln_kernel<<<ROWS / 4, 256, 0, stream>>>(x, n1g, n1b, R1);
  gemmW<0><<<784 * 3, 512, 0, stream>>>(R1, wqT, qkv_b, R2, nullptr, nullptr, nullptr, nullptr, ROWS, 768, 256, 3);
  attn_kernel<<<(2048 * 8) / 4, 256, 0, stream>>>(R2, mask, R1);
  gemmW<1><<<784 * 1, 512, 0, stream>>>(R1, wpT, proj_b, x2, x, n2g, n2b, R1, ROWS, 256, 256, 1);
  gemmW<2><<<784 * 4, 512, 0, stream>>>(R1, w1T, fc1_b, R2, nullptr, nullptr, nullptr, nullptr, ROWS, 1024, 256, 4);
  gemmW<3><<<784 * 1, 512, 0, stream>>>(R2, w2T, fc2_b, d_out, x2, nullptr, nullptr, nullptr, ROWS, 256, 1024, 1);
}